// Round 1
// baseline (5556.468 us; speedup 1.0000x reference)
//
#include <hip/hip_runtime.h>
#include <hip/hip_bf16.h>

#define NN 8192
#define DD 64
#define NITER 100

typedef unsigned short u16;
typedef unsigned int u32;

static constexpr float INV_EPS = 10.0f;        // 1/epsilon
static constexpr float MARG    = 1.0f / 8192.0f; // a_i = b_j = u0_i = 1/n

// Unpack 8 bf16 (packed in uint4) -> 8 f32 (exact: bf16 is truncated f32)
__device__ __forceinline__ void unpack8(const uint4 q, float f[8]) {
  f[0] = __uint_as_float(q.x << 16); f[1] = __uint_as_float(q.x & 0xffff0000u);
  f[2] = __uint_as_float(q.y << 16); f[3] = __uint_as_float(q.y & 0xffff0000u);
  f[4] = __uint_as_float(q.z << 16); f[5] = __uint_as_float(q.z & 0xffff0000u);
  f[6] = __uint_as_float(q.w << 16); f[7] = __uint_as_float(q.w & 0xffff0000u);
}

// ---------------------------------------------------------------------------
// Kernel 1: row norms of x and y. 16384 threads, one row each.
__global__ __launch_bounds__(256) void norms_k(const float* __restrict__ x,
                                               const float* __restrict__ y,
                                               float* __restrict__ xx,
                                               float* __restrict__ yy) {
  int idx = blockIdx.x * 256 + threadIdx.x;       // 0..16383
  const float* src = (idx < NN) ? (x + (size_t)idx * DD)
                                : (y + (size_t)(idx - NN) * DD);
  const float4* p = (const float4*)src;
  float s = 0.f;
#pragma unroll
  for (int i = 0; i < 16; i++) {
    float4 v = p[i];
    s += v.x * v.x + v.y * v.y + v.z * v.z + v.w * v.w;
  }
  if (idx < NN) xx[idx] = s; else yy[idx - NN] = s;
}

// ---------------------------------------------------------------------------
// Kernel 2: build K (bf16). Block = 16 rows x all cols; thread: row t/16,
// 8 consecutive cols. x row held in 16 float4 regs; y read from L2 (2 MB,
// L2-resident). Writes coalesced 16B per lane.
__global__ __launch_bounds__(256) void build_k(const float* __restrict__ x,
                                               const float* __restrict__ y,
                                               const float* __restrict__ xx,
                                               const float* __restrict__ yy,
                                               u16* __restrict__ K) {
  int t  = threadIdx.x;
  int r  = t >> 4;            // 0..15
  int c8 = (t & 15) * 8;      // 0..120
  int i  = blockIdx.x * 16 + r;

  float4 xr[16];
  const float4* xp = (const float4*)(x + (size_t)i * DD);
#pragma unroll
  for (int q = 0; q < 16; q++) xr[q] = xp[q];
  float xn = xx[i];

  for (int jt = 0; jt < NN / 128; jt++) {
    int j0 = jt * 128 + c8;
    float acc[8];
#pragma unroll
    for (int k = 0; k < 8; k++) acc[k] = 0.f;
#pragma unroll 4
    for (int q = 0; q < 16; q++) {
      float4 xv = xr[q];
#pragma unroll
      for (int k = 0; k < 8; k++) {
        float4 yv = *(const float4*)(y + (size_t)(j0 + k) * DD + q * 4);
        acc[k] += xv.x * yv.x + xv.y * yv.y + xv.z * yv.z + xv.w * yv.w;
      }
    }
    u16 outp[8];
#pragma unroll
    for (int k = 0; k < 8; k++) {
      float sq = xn + yy[j0 + k] - 2.f * acc[k];
      sq = fmaxf(sq, 1e-12f);
      float kv = __expf(-sqrtf(sq) * INV_EPS);
      __hip_bfloat16 h = __float2bfloat16(kv);
      outp[k] = *reinterpret_cast<u16*>(&h);
    }
    *(uint4*)(K + (size_t)i * NN + j0) = *(uint4*)outp;
  }
}

// ---------------------------------------------------------------------------
// Kernel 3: initial column partials P[b][j] = sum_{i in block rows} K[i][j]*u0
// (u0 = 1/n constant). Thread owns cols {c*2048 + t*8 + e}.
__global__ __launch_bounds__(256) void col0_k(const u16* __restrict__ K,
                                              float* __restrict__ P) {
  int t = threadIdx.x;
  int b = blockIdx.x;
  int i0 = b * 16;
  float acc[4][8];
#pragma unroll
  for (int c = 0; c < 4; c++)
#pragma unroll
    for (int e = 0; e < 8; e++) acc[c][e] = 0.f;

  for (int r = 0; r < 16; r++) {
#pragma unroll
    for (int c = 0; c < 4; c++) {
      uint4 q = *(const uint4*)(K + (size_t)(i0 + r) * NN + c * 2048 + t * 8);
      float f[8];
      unpack8(q, f);
#pragma unroll
      for (int e = 0; e < 8; e++) acc[c][e] += f[e];
    }
  }
#pragma unroll
  for (int c = 0; c < 4; c++) {
    float4 lo = {acc[c][0] * MARG, acc[c][1] * MARG, acc[c][2] * MARG, acc[c][3] * MARG};
    float4 hi = {acc[c][4] * MARG, acc[c][5] * MARG, acc[c][6] * MARG, acc[c][7] * MARG};
    float* dst = P + (size_t)b * NN + c * 2048 + t * 8;
    *(float4*)dst = lo;
    *(float4*)(dst + 4) = hi;
  }
}

// ---------------------------------------------------------------------------
// Kernel 4: reduce partials + compute v[j] = b_j / sum_k P[k][j].
// 256 blocks x 32 cols. Thread (jj=t&31, kk=t>>5) sums 64 of the 512 partials.
__global__ __launch_bounds__(256) void red_k(const float* __restrict__ P,
                                             float* __restrict__ v) {
  int t = threadIdx.x;
  int j0 = blockIdx.x * 32;
  int jj = t & 31;
  int kk = t >> 5;
  float s = 0.f;
#pragma unroll 8
  for (int k = kk * 64; k < kk * 64 + 64; k++)
    s += P[(size_t)k * NN + j0 + jj];
  __shared__ float red[256];
  red[t] = s;
  __syncthreads();
  if (t < 32) {
    float tot = 0.f;
#pragma unroll
    for (int k = 0; k < 8; k++) tot += red[k * 32 + t];
    v[j0 + t] = MARG / tot;
  }
}

// ---------------------------------------------------------------------------
// Kernel 5 (the hot one): fused row-dot + column-partial.
// Per block: 16 rows. For each row i: s_i = K[i,:].v ; u_i = a/s_i ;
// P_partial[j] += K[i][j]*u_i  (row data reused from registers).
__global__ __launch_bounds__(256) void fused_k(const u16* __restrict__ K,
                                               const float* __restrict__ vin,
                                               float* __restrict__ uout,
                                               float* __restrict__ P) {
  int t = threadIdx.x;
  int b = blockIdx.x;
  int i0 = b * 16;

  // v values for this thread's 32 columns
  float vv[4][8];
#pragma unroll
  for (int c = 0; c < 4; c++) {
    const float* vp = vin + c * 2048 + t * 8;
    float4 a = *(const float4*)vp;
    float4 bq = *(const float4*)(vp + 4);
    vv[c][0] = a.x;  vv[c][1] = a.y;  vv[c][2] = a.z;  vv[c][3] = a.w;
    vv[c][4] = bq.x; vv[c][5] = bq.y; vv[c][6] = bq.z; vv[c][7] = bq.w;
  }

  float acc[4][8];
#pragma unroll
  for (int c = 0; c < 4; c++)
#pragma unroll
    for (int e = 0; e < 8; e++) acc[c][e] = 0.f;

  __shared__ float red[2][256];
  __shared__ float ubc[2];

  for (int rb = 0; rb < 8; rb++) {
    int i = i0 + rb * 2;
    uint4 q0[4], q1[4];
#pragma unroll
    for (int c = 0; c < 4; c++) {
      q0[c] = *(const uint4*)(K + (size_t)i * NN + c * 2048 + t * 8);
      q1[c] = *(const uint4*)(K + (size_t)(i + 1) * NN + c * 2048 + t * 8);
    }
    float s0 = 0.f, s1 = 0.f;
#pragma unroll
    for (int c = 0; c < 4; c++) {
      float f[8];
      unpack8(q0[c], f);
#pragma unroll
      for (int e = 0; e < 8; e++) s0 += f[e] * vv[c][e];
      unpack8(q1[c], f);
#pragma unroll
      for (int e = 0; e < 8; e++) s1 += f[e] * vv[c][e];
    }
    red[0][t] = s0;
    red[1][t] = s1;
    __syncthreads();
    int w = t >> 6, l = t & 63;
    if (w < 2) {
      float val = red[w][l] + red[w][l + 64] + red[w][l + 128] + red[w][l + 192];
#pragma unroll
      for (int o = 32; o > 0; o >>= 1) val += __shfl_xor(val, o);
      if (l == 0) {
        float uv = MARG / val;
        uout[i + w] = uv;
        ubc[w] = uv;
      }
    }
    __syncthreads();
    float u0 = ubc[0], u1 = ubc[1];
#pragma unroll
    for (int c = 0; c < 4; c++) {
      float f[8];
      unpack8(q0[c], f);
#pragma unroll
      for (int e = 0; e < 8; e++) acc[c][e] += f[e] * u0;
      unpack8(q1[c], f);
#pragma unroll
      for (int e = 0; e < 8; e++) acc[c][e] += f[e] * u1;
    }
  }

#pragma unroll
  for (int c = 0; c < 4; c++) {
    float4 lo = {acc[c][0], acc[c][1], acc[c][2], acc[c][3]};
    float4 hi = {acc[c][4], acc[c][5], acc[c][6], acc[c][7]};
    float* dst = P + (size_t)b * NN + c * 2048 + t * 8;
    *(float4*)dst = lo;
    *(float4*)(dst + 4) = hi;
  }
}

// ---------------------------------------------------------------------------
// Kernel 6: pi[i][j] = u_i * K[i][j] * v_j  (f32 out, 256 MB write)
__global__ __launch_bounds__(256) void pi_k(const u16* __restrict__ K,
                                            const float* __restrict__ u,
                                            const float* __restrict__ v,
                                            float* __restrict__ out) {
  int t = threadIdx.x;
  int b = blockIdx.x;
  int i0 = b * 16;

  float vv[4][8];
#pragma unroll
  for (int c = 0; c < 4; c++) {
    const float* vp = v + c * 2048 + t * 8;
    float4 a = *(const float4*)vp;
    float4 bq = *(const float4*)(vp + 4);
    vv[c][0] = a.x;  vv[c][1] = a.y;  vv[c][2] = a.z;  vv[c][3] = a.w;
    vv[c][4] = bq.x; vv[c][5] = bq.y; vv[c][6] = bq.z; vv[c][7] = bq.w;
  }

  for (int r = 0; r < 16; r++) {
    int i = i0 + r;
    float uv = u[i];
#pragma unroll
    for (int c = 0; c < 4; c++) {
      uint4 q = *(const uint4*)(K + (size_t)i * NN + c * 2048 + t * 8);
      float f[8];
      unpack8(q, f);
      float4 lo = {uv * f[0] * vv[c][0], uv * f[1] * vv[c][1],
                   uv * f[2] * vv[c][2], uv * f[3] * vv[c][3]};
      float4 hi = {uv * f[4] * vv[c][4], uv * f[5] * vv[c][5],
                   uv * f[6] * vv[c][6], uv * f[7] * vv[c][7]};
      float* dst = out + (size_t)i * NN + c * 2048 + t * 8;
      *(float4*)dst = lo;
      *(float4*)(dst + 4) = hi;
    }
  }
}

// ---------------------------------------------------------------------------
extern "C" void kernel_launch(void* const* d_in, const int* in_sizes, int n_in,
                              void* d_out, int out_size, void* d_ws, size_t ws_size,
                              hipStream_t stream) {
  const float* x = (const float*)d_in[0];
  const float* y = (const float*)d_in[1];
  float* out = (float*)d_out;

  char* ws = (char*)d_ws;
  u16*  K  = (u16*)ws;                                     // 128 MiB
  float* P = (float*)(ws + (size_t)NN * NN * 2);           // 16 MiB (512 x 8192)
  float* xx = (float*)(ws + (size_t)NN * NN * 2 + (size_t)512 * NN * 4);
  float* yy = xx + NN;
  float* u  = yy + NN;
  float* v  = u + NN;

  norms_k<<<(2 * NN) / 256, 256, 0, stream>>>(x, y, xx, yy);
  build_k<<<NN / 16, 256, 0, stream>>>(x, y, xx, yy, K);
  col0_k<<<NN / 16, 256, 0, stream>>>(K, P);               // P = partials of K^T u0

  for (int it = 0; it < NITER; it++) {
    red_k<<<NN / 32, 256, 0, stream>>>(P, v);              // v = b / (K^T u)
    fused_k<<<NN / 16, 256, 0, stream>>>(K, v, u, P);      // u = a/(Kv); P = partials K^T u
  }
  red_k<<<NN / 32, 256, 0, stream>>>(P, v);                // final v
  pi_k<<<NN / 16, 256, 0, stream>>>(K, u, v, out);         // pi = u * K * v
}

// Round 2
// 3707.549 us; speedup vs baseline: 1.4987x; 1.4987x over previous
//
#include <hip/hip_runtime.h>
#include <hip/hip_bf16.h>

#define NN 8192
#define DD 64
#define NITER 100

typedef unsigned short u16;
typedef unsigned int u32;

static constexpr float INV_EPS = 10.0f;          // 1/epsilon
static constexpr float MARG    = 1.0f / 8192.0f; // a_i = b_j = u0_i = 1/n

// Unpack 8 bf16 (packed in uint4) -> 8 f32 (exact: bf16 is truncated f32)
__device__ __forceinline__ void unpack8(const uint4 q, float f[8]) {
  f[0] = __uint_as_float(q.x << 16); f[1] = __uint_as_float(q.x & 0xffff0000u);
  f[2] = __uint_as_float(q.y << 16); f[3] = __uint_as_float(q.y & 0xffff0000u);
  f[4] = __uint_as_float(q.z << 16); f[5] = __uint_as_float(q.z & 0xffff0000u);
  f[6] = __uint_as_float(q.w << 16); f[7] = __uint_as_float(q.w & 0xffff0000u);
}

// ---------------------------------------------------------------------------
// Kernel 1: row norms of x and y. 16384 threads, one row each.
__global__ __launch_bounds__(256) void norms_k(const float* __restrict__ x,
                                               const float* __restrict__ y,
                                               float* __restrict__ xx,
                                               float* __restrict__ yy) {
  int idx = blockIdx.x * 256 + threadIdx.x;       // 0..16383
  const float* src = (idx < NN) ? (x + (size_t)idx * DD)
                                : (y + (size_t)(idx - NN) * DD);
  const float4* p = (const float4*)src;
  float s = 0.f;
#pragma unroll
  for (int i = 0; i < 16; i++) {
    float4 v = p[i];
    s += v.x * v.x + v.y * v.y + v.z * v.z + v.w * v.w;
  }
  if (idx < NN) xx[idx] = s; else yy[idx - NN] = s;
}

// ---------------------------------------------------------------------------
// Kernel 2 (rewritten): build K (bf16) as LDS-tiled f32 GEMM.
// Block = 256 threads, tile = 64 rows x 128 cols, K-dim = 64 (full).
// x-tile and y-tile staged TRANSPOSED in LDS: xs[k][row], ys[k][col], so the
// main loop does ds_read_b128 of 4 rows / 8 cols per k. Micro-tile 4x8/thread.
// Grid = 128 row-blocks x 64 col-blocks = 8192 blocks.
__global__ __launch_bounds__(256) void build_k(const float* __restrict__ x,
                                               const float* __restrict__ y,
                                               const float* __restrict__ xx,
                                               const float* __restrict__ yy,
                                               u16* __restrict__ K) {
  __shared__ float xs[64][64];    // [k][row]  16 KB
  __shared__ float ys[64][128];   // [k][col]  32 KB

  int t  = threadIdx.x;
  int ib = blockIdx.x & 127;      // row block 0..127
  int jb = blockIdx.x >> 7;       // col block 0..63
  int i0 = ib * 64;
  int j0 = jb * 128;

  // stage x tile (64 rows x 64): thread t reads row t>>2, k-chunk (t&3)*16,
  // coalesced float4 across lane quads; transposed write (4-way bank, 16 wr).
  {
    int row = t >> 2, kc = (t & 3) * 16;
    const float4* src = (const float4*)(x + (size_t)(i0 + row) * DD + kc);
#pragma unroll
    for (int c = 0; c < 4; c++) {
      float4 v = src[c];
      xs[kc + c * 4 + 0][row] = v.x;
      xs[kc + c * 4 + 1][row] = v.y;
      xs[kc + c * 4 + 2][row] = v.z;
      xs[kc + c * 4 + 3][row] = v.w;
    }
  }
  // stage y tile (128 cols x 64): thread t reads y-row (=col) t>>1, k-chunk
  // (t&1)*32; transposed write is 2-way bank (free).
  {
    int col = t >> 1, kc = (t & 1) * 32;
    const float4* src = (const float4*)(y + (size_t)(j0 + col) * DD + kc);
#pragma unroll
    for (int c = 0; c < 8; c++) {
      float4 v = src[c];
      ys[kc + c * 4 + 0][col] = v.x;
      ys[kc + c * 4 + 1][col] = v.y;
      ys[kc + c * 4 + 2][col] = v.z;
      ys[kc + c * 4 + 3][col] = v.w;
    }
  }
  __syncthreads();

  int tr = (t >> 4) * 4;          // row offset within tile: 0,4,..,60
  int tc = (t & 15) * 8;          // col offset within tile: 0,8,..,120

  float acc[4][8];
#pragma unroll
  for (int r = 0; r < 4; r++)
#pragma unroll
    for (int c = 0; c < 8; c++) acc[r][c] = 0.f;

#pragma unroll 4
  for (int k = 0; k < DD; k++) {
    float4 xa = *(const float4*)&xs[k][tr];
    float4 y0 = *(const float4*)&ys[k][tc];
    float4 y1 = *(const float4*)&ys[k][tc + 4];
    float xv[4] = {xa.x, xa.y, xa.z, xa.w};
    float yv[8] = {y0.x, y0.y, y0.z, y0.w, y1.x, y1.y, y1.z, y1.w};
#pragma unroll
    for (int r = 0; r < 4; r++)
#pragma unroll
      for (int c = 0; c < 8; c++) acc[r][c] += xv[r] * yv[c];
  }

  // epilogue: sq = |x|^2 + |y|^2 - 2*dot ; K = exp(-sqrt(sq)/eps) -> bf16
  float xn[4], yn[8];
#pragma unroll
  for (int r = 0; r < 4; r++) xn[r] = xx[i0 + tr + r];
#pragma unroll
  for (int c = 0; c < 8; c++) yn[c] = yy[j0 + tc + c];

#pragma unroll
  for (int r = 0; r < 4; r++) {
    u16 outp[8];
#pragma unroll
    for (int c = 0; c < 8; c++) {
      float sq = xn[r] + yn[c] - 2.f * acc[r][c];
      sq = fmaxf(sq, 1e-12f);
      float kv = __expf(-sqrtf(sq) * INV_EPS);
      __hip_bfloat16 h = __float2bfloat16(kv);
      outp[c] = *reinterpret_cast<u16*>(&h);
    }
    *(uint4*)(K + (size_t)(i0 + tr + r) * NN + j0 + tc) = *(uint4*)outp;
  }
}

// ---------------------------------------------------------------------------
// Kernel 3: initial column partials P[b][j] = sum_{i in block rows} K[i][j]*u0
// (u0 = 1/n constant). Thread owns cols {c*2048 + t*8 + e}.
__global__ __launch_bounds__(256) void col0_k(const u16* __restrict__ K,
                                              float* __restrict__ P) {
  int t = threadIdx.x;
  int b = blockIdx.x;
  int i0 = b * 16;
  float acc[4][8];
#pragma unroll
  for (int c = 0; c < 4; c++)
#pragma unroll
    for (int e = 0; e < 8; e++) acc[c][e] = 0.f;

  for (int r = 0; r < 16; r++) {
#pragma unroll
    for (int c = 0; c < 4; c++) {
      uint4 q = *(const uint4*)(K + (size_t)(i0 + r) * NN + c * 2048 + t * 8);
      float f[8];
      unpack8(q, f);
#pragma unroll
      for (int e = 0; e < 8; e++) acc[c][e] += f[e];
    }
  }
#pragma unroll
  for (int c = 0; c < 4; c++) {
    float4 lo = {acc[c][0] * MARG, acc[c][1] * MARG, acc[c][2] * MARG, acc[c][3] * MARG};
    float4 hi = {acc[c][4] * MARG, acc[c][5] * MARG, acc[c][6] * MARG, acc[c][7] * MARG};
    float* dst = P + (size_t)b * NN + c * 2048 + t * 8;
    *(float4*)dst = lo;
    *(float4*)(dst + 4) = hi;
  }
}

// ---------------------------------------------------------------------------
// Kernel 4: reduce partials + compute v[j] = b_j / sum_k P[k][j].
// 256 blocks x 32 cols. Thread (jj=t&31, kk=t>>5) sums 64 of the 512 partials.
__global__ __launch_bounds__(256) void red_k(const float* __restrict__ P,
                                             float* __restrict__ v) {
  int t = threadIdx.x;
  int j0 = blockIdx.x * 32;
  int jj = t & 31;
  int kk = t >> 5;
  float s = 0.f;
#pragma unroll 8
  for (int k = kk * 64; k < kk * 64 + 64; k++)
    s += P[(size_t)k * NN + j0 + jj];
  __shared__ float red[256];
  red[t] = s;
  __syncthreads();
  if (t < 32) {
    float tot = 0.f;
#pragma unroll
    for (int k = 0; k < 8; k++) tot += red[k * 32 + t];
    v[j0 + t] = MARG / tot;
  }
}

// ---------------------------------------------------------------------------
// Kernel 5 (the hot one): fused row-dot + column-partial.
// Per block: 16 rows. For each row i: s_i = K[i,:].v ; u_i = a/s_i ;
// P_partial[j] += K[i][j]*u_i  (row data reused from registers).
__global__ __launch_bounds__(256) void fused_k(const u16* __restrict__ K,
                                               const float* __restrict__ vin,
                                               float* __restrict__ uout,
                                               float* __restrict__ P) {
  int t = threadIdx.x;
  int b = blockIdx.x;
  int i0 = b * 16;

  // v values for this thread's 32 columns
  float vv[4][8];
#pragma unroll
  for (int c = 0; c < 4; c++) {
    const float* vp = vin + c * 2048 + t * 8;
    float4 a = *(const float4*)vp;
    float4 bq = *(const float4*)(vp + 4);
    vv[c][0] = a.x;  vv[c][1] = a.y;  vv[c][2] = a.z;  vv[c][3] = a.w;
    vv[c][4] = bq.x; vv[c][5] = bq.y; vv[c][6] = bq.z; vv[c][7] = bq.w;
  }

  float acc[4][8];
#pragma unroll
  for (int c = 0; c < 4; c++)
#pragma unroll
    for (int e = 0; e < 8; e++) acc[c][e] = 0.f;

  __shared__ float red[2][256];
  __shared__ float ubc[2];

  for (int rb = 0; rb < 8; rb++) {
    int i = i0 + rb * 2;
    uint4 q0[4], q1[4];
#pragma unroll
    for (int c = 0; c < 4; c++) {
      q0[c] = *(const uint4*)(K + (size_t)i * NN + c * 2048 + t * 8);
      q1[c] = *(const uint4*)(K + (size_t)(i + 1) * NN + c * 2048 + t * 8);
    }
    float s0 = 0.f, s1 = 0.f;
#pragma unroll
    for (int c = 0; c < 4; c++) {
      float f[8];
      unpack8(q0[c], f);
#pragma unroll
      for (int e = 0; e < 8; e++) s0 += f[e] * vv[c][e];
      unpack8(q1[c], f);
#pragma unroll
      for (int e = 0; e < 8; e++) s1 += f[e] * vv[c][e];
    }
    red[0][t] = s0;
    red[1][t] = s1;
    __syncthreads();
    int w = t >> 6, l = t & 63;
    if (w < 2) {
      float val = red[w][l] + red[w][l + 64] + red[w][l + 128] + red[w][l + 192];
#pragma unroll
      for (int o = 32; o > 0; o >>= 1) val += __shfl_xor(val, o);
      if (l == 0) {
        float uv = MARG / val;
        uout[i + w] = uv;
        ubc[w] = uv;
      }
    }
    __syncthreads();
    float u0 = ubc[0], u1 = ubc[1];
#pragma unroll
    for (int c = 0; c < 4; c++) {
      float f[8];
      unpack8(q0[c], f);
#pragma unroll
      for (int e = 0; e < 8; e++) acc[c][e] += f[e] * u0;
      unpack8(q1[c], f);
#pragma unroll
      for (int e = 0; e < 8; e++) acc[c][e] += f[e] * u1;
    }
  }

#pragma unroll
  for (int c = 0; c < 4; c++) {
    float4 lo = {acc[c][0], acc[c][1], acc[c][2], acc[c][3]};
    float4 hi = {acc[c][4], acc[c][5], acc[c][6], acc[c][7]};
    float* dst = P + (size_t)b * NN + c * 2048 + t * 8;
    *(float4*)dst = lo;
    *(float4*)(dst + 4) = hi;
  }
}

// ---------------------------------------------------------------------------
// Kernel 6: pi[i][j] = u_i * K[i][j] * v_j  (f32 out, 256 MB write)
__global__ __launch_bounds__(256) void pi_k(const u16* __restrict__ K,
                                            const float* __restrict__ u,
                                            const float* __restrict__ v,
                                            float* __restrict__ out) {
  int t = threadIdx.x;
  int b = blockIdx.x;
  int i0 = b * 16;

  float vv[4][8];
#pragma unroll
  for (int c = 0; c < 4; c++) {
    const float* vp = v + c * 2048 + t * 8;
    float4 a = *(const float4*)vp;
    float4 bq = *(const float4*)(vp + 4);
    vv[c][0] = a.x;  vv[c][1] = a.y;  vv[c][2] = a.z;  vv[c][3] = a.w;
    vv[c][4] = bq.x; vv[c][5] = bq.y; vv[c][6] = bq.z; vv[c][7] = bq.w;
  }

  for (int r = 0; r < 16; r++) {
    int i = i0 + r;
    float uv = u[i];
#pragma unroll
    for (int c = 0; c < 4; c++) {
      uint4 q = *(const uint4*)(K + (size_t)i * NN + c * 2048 + t * 8);
      float f[8];
      unpack8(q, f);
      float4 lo = {uv * f[0] * vv[c][0], uv * f[1] * vv[c][1],
                   uv * f[2] * vv[c][2], uv * f[3] * vv[c][3]};
      float4 hi = {uv * f[4] * vv[c][4], uv * f[5] * vv[c][5],
                   uv * f[6] * vv[c][6], uv * f[7] * vv[c][7]};
      float* dst = out + (size_t)i * NN + c * 2048 + t * 8;
      *(float4*)dst = lo;
      *(float4*)(dst + 4) = hi;
    }
  }
}

// ---------------------------------------------------------------------------
extern "C" void kernel_launch(void* const* d_in, const int* in_sizes, int n_in,
                              void* d_out, int out_size, void* d_ws, size_t ws_size,
                              hipStream_t stream) {
  const float* x = (const float*)d_in[0];
  const float* y = (const float*)d_in[1];
  float* out = (float*)d_out;

  char* ws = (char*)d_ws;
  u16*  K  = (u16*)ws;                                     // 128 MiB
  float* P = (float*)(ws + (size_t)NN * NN * 2);           // 16 MiB (512 x 8192)
  float* xx = (float*)(ws + (size_t)NN * NN * 2 + (size_t)512 * NN * 4);
  float* yy = xx + NN;
  float* u  = yy + NN;
  float* v  = u + NN;

  norms_k<<<(2 * NN) / 256, 256, 0, stream>>>(x, y, xx, yy);
  build_k<<<128 * 64, 256, 0, stream>>>(x, y, xx, yy, K);
  col0_k<<<NN / 16, 256, 0, stream>>>(K, P);               // P = partials of K^T u0

  for (int it = 0; it < NITER; it++) {
    red_k<<<NN / 32, 256, 0, stream>>>(P, v);              // v = b / (K^T u)
    fused_k<<<NN / 16, 256, 0, stream>>>(K, v, u, P);      // u = a/(Kv); P = partials K^T u
  }
  red_k<<<NN / 32, 256, 0, stream>>>(P, v);                // final v
  pi_k<<<NN / 16, 256, 0, stream>>>(K, u, v, out);         // pi = u * K * v
}